// Round 6
// baseline (318.293 us; speedup 1.0000x reference)
//
#include <hip/hip_runtime.h>
#include <hip/hip_bf16.h>

// SimpleFuzzyAttention: B=2, S=2048, D=1024, H=16, DK=64
// fz(s) is univariate -> packed-pair bf16 LUT of g(s)=exp(fz(s)-max);
// attention = 1-gather LUT lerp + un-normalized softmax. bf16 MFMA GEMMs.
// R5: sequential GEMM launches (L2 working set per XCD: A-band 1MB + B 2MB
// fits 4MB L2 -- the fused z=3 grid thrashed L2 and fell to LLC), XCD-band
// swizzle, explicit LDS double-buffer (1 block/CU has no inter-block overlap),
// LDS-transposed mode-1 epilogue, flash: invh folded into Q scale + no clamps.

#define S_LEN 2048
#define DMODEL 1024
#define NHEAD 16
#define DKH 64
#define NLUT 2048
#define LUT_MIN (-10.0f)
#define LUT_MAX (10.0f)
#define FPAD 72    // Ps row stride (shorts)
#define TPAD 136   // epilogue transpose row stride (shorts): 272B = 17x16B

typedef __attribute__((ext_vector_type(8))) short bfx8;   // 8 bf16 (4 VGPRs)
typedef __attribute__((ext_vector_type(4))) short sx4;    // 4 bf16 (8B)
typedef __attribute__((ext_vector_type(4))) float fx4;    // MFMA C/D

__device__ __forceinline__ short f2bf(float x) {
    unsigned u = __builtin_bit_cast(unsigned, x);
    u = (u + 0x7fffu + ((u >> 16) & 1u)) >> 16;   // RNE
    return (short)u;
}

__device__ __forceinline__ void stage8_f32(const float* __restrict__ src, short* dst) {
    float4 a = *(const float4*)(src);
    float4 b = *(const float4*)(src + 4);
    bfx8 r;
    r[0] = f2bf(a.x); r[1] = f2bf(a.y); r[2] = f2bf(a.z); r[3] = f2bf(a.w);
    r[4] = f2bf(b.x); r[5] = f2bf(b.y); r[6] = f2bf(b.z); r[7] = f2bf(b.w);
    *(bfx8*)dst = r;
}

// global -> LDS direct 16B copy (LDS base wave-uniform; lane*16 implied)
__device__ __forceinline__ void gload_lds16(const void* g, void* l) {
    __builtin_amdgcn_global_load_lds(
        (const __attribute__((address_space(1))) unsigned int*)g,
        (__attribute__((address_space(3))) unsigned int*)l, 16, 0, 0);
}

// ---------------------------------------------------------------------------
// LUT body: lutp[j] = bf16(g[j]) | bf16(g[j+1])<<16, g = exp(fz - max fz)
// ---------------------------------------------------------------------------
__device__ void lut_body(const float* __restrict__ centers, const float* __restrict__ widths,
                         const float* __restrict__ temp, unsigned* __restrict__ lutp) {
    __shared__ float fzb[NLUT];
    __shared__ float red[256];
    __shared__ float cs[48], wsb[48];
    int tid = threadIdx.x;
    if (tid < 48) { cs[tid] = centers[tid]; wsb[tid] = widths[tid]; }
    __syncthreads();
    float invT = 1.0f / temp[0];
    const float step = (LUT_MAX - LUT_MIN) / (float)(NLUT - 1);
    float lmax = -1e30f;
    for (int i = tid; i < NLUT; i += 256) {
        float s = LUT_MIN + step * (float)i;
        float fz = 0.0f;
        #pragma unroll 1
        for (int j = 0; j < 48; j++) {
            float d = s - cs[j];
            float w = wsb[j];
            fz += expf(-(d * d) / (2.0f * w * w));
        }
        fz = fz * (1.0f / 3.0f) * invT;
        fzb[i] = fz;
        lmax = fmaxf(lmax, fz);
    }
    red[tid] = lmax;
    __syncthreads();
    for (int off = 128; off > 0; off >>= 1) {
        if (tid < off) red[tid] = fmaxf(red[tid], red[tid + off]);
        __syncthreads();
    }
    float m = red[0];
    __syncthreads();
    for (int i = tid; i < NLUT; i += 256) fzb[i] = expf(fzb[i] - m);
    __syncthreads();
    for (int i = tid; i < NLUT; i += 256) {
        float g0 = fzb[i];
        float g1 = fzb[(i + 1 < NLUT) ? i + 1 : NLUT - 1];
        unsigned lo = (unsigned short)f2bf(g0);
        unsigned hi = (unsigned short)f2bf(g1);
        lutp[i] = lo | (hi << 16);
    }
}

__global__ void build_lut_pk(const float* centers, const float* widths,
                             const float* temp, unsigned* lutp) {
    lut_body(centers, widths, temp, lutp);
}

__global__ void cast_bf16(const float* __restrict__ src, short* __restrict__ dst, int n8) {
    int i = blockIdx.x * 256 + threadIdx.x;
    if (i < n8) stage8_f32(src + (size_t)i * 8, dst + (size_t)i * 8);
}

// ---------------------------------------------------------------------------
// Fused prep, exact flat grid: [0,6144) inputs, [6144,8192) weights, 8192 LUT
// ---------------------------------------------------------------------------
__global__ void prep_all(const float* q, const float* kin, const float* v,
        const float* wq, const float* wk, const float* wv, const float* wo,
        short* xq, short* xk, short* xv,
        short* bwq, short* bwk, short* bwv, short* bwo,
        const float* centers, const float* widths, const float* temp,
        unsigned* lutp) {
    int bid = blockIdx.x;
    if (bid >= 8192) {
        lut_body(centers, widths, temp, lutp);
        return;
    }
    const float* src; short* dst; int blk;
    if (bid < 6144) {
        int y = bid >> 11; blk = bid & 2047;
        src = (y == 0) ? q : (y == 1) ? kin : v;
        dst = (y == 0) ? xq : (y == 1) ? xk : xv;
    } else {
        int y = (bid - 6144) >> 9; blk = (bid - 6144) & 511;
        src = (y == 0) ? wq : (y == 1) ? wk : (y == 2) ? wv : wo;
        dst = (y == 0) ? bwq : (y == 1) ? bwk : (y == 2) ? bwv : bwo;
    }
    size_t i = (size_t)blk * 256 + threadIdx.x;
    stage8_f32(src + i * 8, (short*)dst + i * 8);
}

// ---------------------------------------------------------------------------
// bf16 BT-GEMM, one job per launch. 128x128 tile, BK=32, explicit LDS double
// buffer, XCD-band swizzle (xcd=f&7 -> 4-tile m-band; per-XCD L2 set = 3MB).
// C[m,n] = (sum_k A[m,k]*W[n,k] + bias[n]) * scale.
// mode 0: bf16 [B,H,S,DK]; 1: bf16 [B,H,DK,S] (LDS-transposed stores); 2: fp32
// ---------------------------------------------------------------------------
struct GemmJob {
    const short* A; const short* W; const float* bias;
    short* obf; float* of32; int mode; float scale;
};

__global__ __launch_bounds__(256, 2) void gemm_sq(GemmJob jb) {
    __shared__ __align__(16) short smem[4][128 * 32];   // As0,As1,Bs0,Bs1 = 32KB
    int tid = threadIdx.x, wave = tid >> 6, lane = tid & 63, quad = lane >> 4, l15 = lane & 15;
    int f = blockIdx.x;
    int idx = f >> 3;
    int n0 = (idx & 7) * 128;
    int m0 = ((f & 7) * 4 + (idx >> 3)) * 128;   // XCD band: f&7 fixes 4-row m-band
    int wm = (wave >> 1) * 64, wn = (wave & 1) * 64;

    fx4 acc[4][4];
    #pragma unroll
    for (int i = 0; i < 4; i++)
        #pragma unroll
        for (int j = 0; j < 4; j++)
            #pragma unroll
            for (int r = 0; r < 4; r++) acc[i][j][r] = 0.0f;

    int fc = (quad ^ ((l15 >> 1) & 3)) * 8;      // swizzled frag chunk (shorts)

    // staging geometry (constant)
    int srow[2], sgc[2], sbase[2];
    #pragma unroll
    for (int r = 0; r < 2; r++) {
        int slot = r * 256 + wave * 64 + lane;
        srow[r] = slot >> 2;
        sgc[r] = (slot & 3) ^ ((srow[r] >> 1) & 3);
        sbase[r] = (r * 256 + wave * 64) * 8;
    }

    // prologue: stage k-tile 0 into buffer 0
    #pragma unroll
    for (int r = 0; r < 2; r++) {
        gload_lds16(jb.A + (size_t)(m0 + srow[r]) * DMODEL + sgc[r] * 8, &smem[0][sbase[r]]);
        gload_lds16(jb.W + (size_t)(n0 + srow[r]) * DMODEL + sgc[r] * 8, &smem[2][sbase[r]]);
    }

    for (int kt = 0; kt < 32; kt++) {
        __syncthreads();                          // buf[kt&1] ready (vmcnt drained here)
        if (kt + 1 < 32) {
            int k0 = (kt + 1) * 32, b = (kt + 1) & 1;
            #pragma unroll
            for (int r = 0; r < 2; r++) {
                gload_lds16(jb.A + (size_t)(m0 + srow[r]) * DMODEL + k0 + sgc[r] * 8,
                            &smem[b][sbase[r]]);
                gload_lds16(jb.W + (size_t)(n0 + srow[r]) * DMODEL + k0 + sgc[r] * 8,
                            &smem[2 + b][sbase[r]]);
            }
        }
        const short* Ab = smem[kt & 1];
        const short* Bb = smem[2 + (kt & 1)];
        bfx8 af[4], bfr[4];
        #pragma unroll
        for (int i = 0; i < 4; i++) af[i] = *(const bfx8*)(&Ab[(wm + i * 16 + l15) * 32 + fc]);
        #pragma unroll
        for (int j = 0; j < 4; j++) bfr[j] = *(const bfx8*)(&Bb[(wn + j * 16 + l15) * 32 + fc]);
        #pragma unroll
        for (int i = 0; i < 4; i++)
            #pragma unroll
            for (int j = 0; j < 4; j++)
                acc[i][j] = __builtin_amdgcn_mfma_f32_16x16x32_bf16(af[i], bfr[j], acc[i][j], 0, 0, 0);
    }

    if (jb.mode == 1) {
        // transpose through LDS -> coalesced 16B stores of VT [B,H,DK,S]
        short* T = smem[0];                      // 64 x TPAD shorts = 17.4KB
        int bb = m0 >> 11, s0 = m0 & 2047;
        #pragma unroll
        for (int half = 0; half < 2; half++) {
            __syncthreads();
            if ((wave & 1) == half) {
                #pragma unroll
                for (int j = 0; j < 4; j++) {
                    int nl = j * 16 + l15;                        // 0..63 within half
                    float bv = jb.bias[n0 + half * 64 + nl];
                    #pragma unroll
                    for (int i = 0; i < 4; i++) {
                        int ml = wm + i * 16 + quad * 4;
                        sx4 w4;
                        #pragma unroll
                        for (int r = 0; r < 4; r++)
                            w4[r] = f2bf((acc[i][j][r] + bv) * jb.scale);
                        *(sx4*)(&T[nl * TPAD + ml]) = w4;
                    }
                }
            }
            __syncthreads();
            #pragma unroll
            for (int r2 = 0; r2 < 4; r2++) {
                int ch = r2 * 256 + tid;                          // 1024 chunks of 16B
                int nl = ch >> 4, m8 = ch & 15;
                int n = n0 + half * 64 + nl;
                int hh = n >> 6, dk = n & 63;
                *(int4*)(jb.obf + (((size_t)(bb * NHEAD + hh)) * DKH + dk) * S_LEN
                         + s0 + m8 * 8) = *(const int4*)(&T[nl * TPAD + m8 * 8]);
            }
        }
        return;
    }

    // modes 0/2: direct stores. C/D layout col=lane&15 (n), row=quad*4+reg (m)
    #pragma unroll
    for (int j = 0; j < 4; j++) {
        int n = n0 + wn + j * 16 + l15;
        float bv = jb.bias[n];
        #pragma unroll
        for (int i = 0; i < 4; i++) {
            #pragma unroll
            for (int r = 0; r < 4; r++) {
                int m = m0 + wm + i * 16 + quad * 4 + r;
                float v = (acc[i][j][r] + bv) * jb.scale;
                if (jb.mode == 0) {
                    int b = m >> 11, s = m & 2047, h = n >> 6, dk = n & 63;
                    jb.obf[(((size_t)(b * NHEAD + h)) * S_LEN + s) * DKH + dk] = f2bf(v);
                } else {
                    jb.of32[(size_t)m * DMODEL + n] = v;
                }
            }
        }
    }
}

// ---------------------------------------------------------------------------
// Fuzzy flash attention. One block = 64 q rows of one (b,h); kv tiles of 64.
// Q pre-scaled by invh/8 at projection -> x = score + 1023.5 directly.
// K/V via global_load_lds + XOR swizzle; wave-private Ps; den via ones-MFMA.
// ---------------------------------------------------------------------------
__global__ __launch_bounds__(256, 4) void flash_fuzzy(const short* __restrict__ Qb,
        const short* __restrict__ Kb, const short* __restrict__ VTb,
        const unsigned* __restrict__ lutg, short* __restrict__ AO) {
    __shared__ __align__(16) short Ks[64 * 64];     // 8 KB, swizzled
    __shared__ __align__(16) short Vs[64 * 64];     // 8 KB, swizzled (VT tile [dk][kv])
    __shared__ __align__(16) short Ps[64 * FPAD];   // 9 KB, padded, wave-private rows
    __shared__ unsigned lut[NLUT];                  // 8 KB packed pairs

    int tid = threadIdx.x, wave = tid >> 6, lane = tid & 63, quad = lane >> 4, l15 = lane & 15;
    int q0 = blockIdx.x * 64, bh = blockIdx.y;
    const short* Qp = Qb + (size_t)bh * S_LEN * DKH;
    const short* Kp = Kb + (size_t)bh * S_LEN * DKH;
    const short* Vp = VTb + (size_t)bh * DKH * S_LEN;

    #pragma unroll
    for (int i = tid; i < NLUT / 4; i += 256)
        ((uint4*)lut)[i] = ((const uint4*)lutg)[i];

    bfx8 aq[2];
    #pragma unroll
    for (int ks = 0; ks < 2; ks++)
        aq[ks] = *(const bfx8*)(Qp + (size_t)(q0 + wave * 16 + l15) * DKH + ks * 32 + quad * 8);

    bfx8 ones;
    #pragma unroll
    for (int i = 0; i < 8; i++) ones[i] = (short)0x3F80;  // bf16 1.0

    fx4 oacc[4];
    fx4 dacc;
    #pragma unroll
    for (int r = 0; r < 4; r++) dacc[r] = 0.0f;
    #pragma unroll
    for (int tn = 0; tn < 4; tn++)
        #pragma unroll
        for (int r = 0; r < 4; r++) oacc[tn][r] = 0.0f;

    int srow[2], sgc[2];
    #pragma unroll
    for (int r = 0; r < 2; r++) {
        int slot = (wave * 2 + r) * 64 + lane;
        srow[r] = slot >> 3;
        sgc[r] = (slot & 7) ^ (srow[r] & 7);
    }

    for (int t0 = 0; t0 < S_LEN; t0 += 64) {
        __syncthreads();
        #pragma unroll
        for (int r = 0; r < 2; r++) {
            gload_lds16(Kp + (size_t)(t0 + srow[r]) * DKH + sgc[r] * 8,
                        &Ks[((wave * 2 + r) * 64) * 8]);
            gload_lds16(Vp + (size_t)srow[r] * S_LEN + t0 + sgc[r] * 8,
                        &Vs[((wave * 2 + r) * 64) * 8]);
        }
        __syncthreads();

        fx4 sac[4];
        #pragma unroll
        for (int tn = 0; tn < 4; tn++)
            #pragma unroll
            for (int r = 0; r < 4; r++) sac[tn][r] = 0.0f;
        #pragma unroll
        for (int ks = 0; ks < 2; ks++) {
            int fcs = ((ks * 4 + quad) ^ (l15 & 7)) * 8;
            bfx8 bk[4];
            #pragma unroll
            for (int tn = 0; tn < 4; tn++)
                bk[tn] = *(const bfx8*)(&Ks[(tn * 16 + l15) * 64 + fcs]);
            #pragma unroll
            for (int tn = 0; tn < 4; tn++)
                sac[tn] = __builtin_amdgcn_mfma_f32_16x16x32_bf16(aq[ks], bk[tn], sac[tn], 0, 0, 0);
        }

        // p = g(s): scores arrive pre-scaled by invh; x = s + 1023.5.
        // scores are ~24 sigma inside the table -> no float clamps; j&2047 guard.
        #pragma unroll
        for (int tn = 0; tn < 4; tn++) {
            #pragma unroll
            for (int r = 0; r < 4; r++) {
                float x = sac[tn][r] + 1023.5f;
                int j = (int)x;
                float ff = x - (float)j;
                unsigned pr = lut[j & (NLUT - 1)];
                float v0 = __builtin_bit_cast(float, pr << 16);
                float v1 = __builtin_bit_cast(float, pr & 0xffff0000u);
                float pv = fmaf(ff, v1 - v0, v0);
                unsigned u = __builtin_bit_cast(unsigned, pv);
                Ps[(wave * 16 + quad * 4 + r) * FPAD + tn * 16 + l15] =
                    (short)((u + 0x8000u) >> 16);
            }
        }
        // NO barrier: Ps rows [wave*16, wave*16+16) are wave-private.

        #pragma unroll
        for (int ks = 0; ks < 2; ks++) {
            int fcs = ((ks * 4 + quad) ^ (l15 & 7)) * 8;
            bfx8 ap, bv[4];
            ap = *(const bfx8*)(&Ps[(wave * 16 + l15) * FPAD + ks * 32 + quad * 8]);
            #pragma unroll
            for (int tn = 0; tn < 4; tn++)
                bv[tn] = *(const bfx8*)(&Vs[(tn * 16 + l15) * 64 + fcs]);
            #pragma unroll
            for (int tn = 0; tn < 4; tn++)
                oacc[tn] = __builtin_amdgcn_mfma_f32_16x16x32_bf16(ap, bv[tn], oacc[tn], 0, 0, 0);
            dacc = __builtin_amdgcn_mfma_f32_16x16x32_bf16(ap, ones, dacc, 0, 0, 0);
        }
    }

    int b = bh >> 4, h = bh & 15;
    #pragma unroll
    for (int tn = 0; tn < 4; tn++) {
        #pragma unroll
        for (int r = 0; r < 4; r++) {
            int q = q0 + wave * 16 + quad * 4 + r;
            int dk = tn * 16 + l15;
            float v = oacc[tn][r] / dacc[r];
            AO[((size_t)(b * S_LEN + q)) * DMODEL + h * DKH + dk] = f2bf(v);
        }
    }
}

// ---------------------------------------------------------------------------
extern "C" void kernel_launch(void* const* d_in, const int* in_sizes, int n_in,
                              void* d_out, int out_size, void* d_ws, size_t ws_size,
                              hipStream_t stream) {
    const float* query   = (const float*)d_in[0];
    const float* key_in  = (const float*)d_in[1];
    const float* value   = (const float*)d_in[2];
    const float* w_q     = (const float*)d_in[3];
    const float* b_q     = (const float*)d_in[4];
    const float* w_k     = (const float*)d_in[5];
    const float* b_k     = (const float*)d_in[6];
    const float* w_v     = (const float*)d_in[7];
    const float* b_v     = (const float*)d_in[8];
    const float* w_o     = (const float*)d_in[9];
    const float* b_o     = (const float*)d_in[10];
    const float* centers = (const float*)d_in[11];
    const float* widths  = (const float*)d_in[12];
    const float* temp    = (const float*)d_in[13];

    char* p = (char*)d_ws;
    auto alloc = [&](size_t bytes) -> void* {
        void* r = (void*)p;
        p += (bytes + 255) & ~(size_t)255;
        return r;
    };
    const size_t nBHSD = (size_t)2 * NHEAD * S_LEN * DKH;    // 4.19M elems
    const size_t nW    = (size_t)DMODEL * DMODEL;            // 1.05M elems
    const float QSCALE = 0.125f * ((float)(NLUT - 1) / (LUT_MAX - LUT_MIN));  // 1/8 * invh

    unsigned* lutp = (unsigned*)alloc(NLUT * 4);
    short* Qb  = (short*)alloc(nBHSD * 2);
    short* Kb  = (short*)alloc(nBHSD * 2);
    short* VTb = (short*)alloc(nBHSD * 2);

    char* save = p;
    short* xq  = (short*)alloc(nBHSD * 2);
    short* xk  = (short*)alloc(nBHSD * 2);
    short* xv  = (short*)alloc(nBHSD * 2);
    short* bwq = (short*)alloc(nW * 2);
    short* bwk = (short*)alloc(nW * 2);
    short* bwv = (short*)alloc(nW * 2);
    short* bwo = (short*)alloc(nW * 2);
    bool fused = ((size_t)(p - (char*)d_ws) <= ws_size);

    dim3 blk(256), gg(256), fg(32, 32);
    GemmJob J;

    if (fused) {
        short* AO = xq;   // alias: xq dead after Q gemm... (dead after its gemm; reused post-flash)
        prep_all<<<dim3(8193), blk, 0, stream>>>(query, key_in, value, w_q, w_k, w_v, w_o,
                xq, xk, xv, bwq, bwk, bwv, bwo, centers, widths, temp, lutp);
        J = {xq, bwq, b_q, Qb,  nullptr, 0, QSCALE};
        gemm_sq<<<gg, blk, 0, stream>>>(J);
        J = {xk, bwk, b_k, Kb,  nullptr, 0, 1.0f};
        gemm_sq<<<gg, blk, 0, stream>>>(J);
        J = {xv, bwv, b_v, VTb, nullptr, 1, 1.0f};
        gemm_sq<<<gg, blk, 0, stream>>>(J);
        flash_fuzzy<<<fg, blk, 0, stream>>>(Qb, Kb, VTb, lutp, AO);
        J = {AO, bwo, b_o, nullptr, (float*)d_out, 2, 1.0f};
        gemm_sq<<<gg, blk, 0, stream>>>(J);
    } else {
        // serial fallback: reuse one x-buffer + one w-buffer (~36 MB total)
        p = save;
        short* xf = (short*)alloc(nBHSD * 2);
        short* wb = (short*)alloc(nW * 2);
        short* AO = xf;
        const int n8x = (int)(nBHSD / 8), n8w = (int)(nW / 8);
        dim3 cg((n8x + 255) / 256), cw((n8w + 255) / 256);
        build_lut_pk<<<dim3(1), blk, 0, stream>>>(centers, widths, temp, lutp);
        cast_bf16<<<cg, blk, 0, stream>>>(query, xf, n8x);
        cast_bf16<<<cw, blk, 0, stream>>>(w_q, wb, n8w);
        J = {xf, wb, b_q, Qb, nullptr, 0, QSCALE};
        gemm_sq<<<gg, blk, 0, stream>>>(J);
        cast_bf16<<<cg, blk, 0, stream>>>(key_in, xf, n8x);
        cast_bf16<<<cw, blk, 0, stream>>>(w_k, wb, n8w);
        J = {xf, wb, b_k, Kb, nullptr, 0, 1.0f};
        gemm_sq<<<gg, blk, 0, stream>>>(J);
        cast_bf16<<<cg, blk, 0, stream>>>(value, xf, n8x);
        cast_bf16<<<cw, blk, 0, stream>>>(w_v, wb, n8w);
        J = {xf, wb, b_v, VTb, nullptr, 1, 1.0f};
        gemm_sq<<<gg, blk, 0, stream>>>(J);
        flash_fuzzy<<<fg, blk, 0, stream>>>(Qb, Kb, VTb, lutp, AO);
        cast_bf16<<<cw, blk, 0, stream>>>(w_o, wb, n8w);
        J = {AO, wb, b_o, nullptr, (float*)d_out, 2, 1.0f};
        gemm_sq<<<gg, blk, 0, stream>>>(J);
    }
}